// Round 3
// baseline (280.634 us; speedup 1.0000x reference)
//
#include <hip/hip_runtime.h>

// RX(theta) on `qubit` of a [B, 2^nq] complex state (real/imag split, fp32).
//   nr0 = c*r0 + s*i1 ; ni0 = c*i0 - s*r1
//   nr1 = c*r1 + s*i0 ; ni1 = c*i1 - s*r0
// c = cos(theta/2), s = sin(theta/2), pair stride = right = 2^(nq-q-1).
//
// Pure stream (read-once/write-once): nontemporal 16B loads/stores via
// native clang vectors, 8 pairs per thread to amortize index arithmetic.

typedef float f32x4 __attribute__((ext_vector_type(4)));

__global__ void __launch_bounds__(256)
rx_gate_kernel(const float* __restrict__ sr,
               const float* __restrict__ si,
               const float* __restrict__ theta,
               const int* __restrict__ qubit_p,
               const int* __restrict__ nq_p,
               float* __restrict__ out_r,
               float* __restrict__ out_i,
               long long npairs) {
    long long t = (long long)blockIdx.x * blockDim.x + threadIdx.x;
    long long p = t * 8;  // first pair index handled by this thread
    if (p >= npairs) return;

    const int shift = nq_p[0] - qubit_p[0] - 1;   // log2(right)
    const long long right = 1ll << shift;
    const long long mask = right - 1;

    const float half = 0.5f * theta[0];
    const float c = cosf(half);
    const float s = sinf(half);

    if (((right & 7) == 0) && (p + 8 <= npairs)) {
        // vector path: 8 consecutive pairs = 2x 16B per stream, contiguous
        const long long idx0 = ((p >> shift) << (shift + 1)) | (p & mask);

        f32x4 R0[2], R1[2], I0[2], I1[2];
#pragma unroll
        for (int v = 0; v < 2; ++v) {
            R0[v] = __builtin_nontemporal_load((const f32x4*)(sr + idx0 + 4 * v));
            R1[v] = __builtin_nontemporal_load((const f32x4*)(sr + idx0 + right + 4 * v));
            I0[v] = __builtin_nontemporal_load((const f32x4*)(si + idx0 + 4 * v));
            I1[v] = __builtin_nontemporal_load((const f32x4*)(si + idx0 + right + 4 * v));
        }

        f32x4 NR0[2], NR1[2], NI0[2], NI1[2];
#pragma unroll
        for (int v = 0; v < 2; ++v) {
#pragma unroll
            for (int k = 0; k < 4; ++k) {
                NR0[v][k] = fmaf(c, R0[v][k],  s * I1[v][k]);
                NI0[v][k] = fmaf(c, I0[v][k], -s * R1[v][k]);
                NR1[v][k] = fmaf(c, R1[v][k],  s * I0[v][k]);
                NI1[v][k] = fmaf(c, I1[v][k], -s * R0[v][k]);
            }
        }

#pragma unroll
        for (int v = 0; v < 2; ++v) {
            __builtin_nontemporal_store(NR0[v], (f32x4*)(out_r + idx0 + 4 * v));
            __builtin_nontemporal_store(NR1[v], (f32x4*)(out_r + idx0 + right + 4 * v));
            __builtin_nontemporal_store(NI0[v], (f32x4*)(out_i + idx0 + 4 * v));
            __builtin_nontemporal_store(NI1[v], (f32x4*)(out_i + idx0 + right + 4 * v));
        }
    } else {
        // scalar fallback (tail, or right < 8)
        for (int k = 0; k < 8; ++k) {
            const long long pk = p + k;
            if (pk >= npairs) break;
            const long long idx = ((pk >> shift) << (shift + 1)) | (pk & mask);
            const float r0 = sr[idx];
            const float r1 = sr[idx + right];
            const float i0 = si[idx];
            const float i1 = si[idx + right];
            out_r[idx]         = fmaf(c, r0,  s * i1);
            out_i[idx]         = fmaf(c, i0, -s * r1);
            out_r[idx + right] = fmaf(c, r1,  s * i0);
            out_i[idx + right] = fmaf(c, i1, -s * r0);
        }
    }
}

extern "C" void kernel_launch(void* const* d_in, const int* in_sizes, int n_in,
                              void* d_out, int out_size, void* d_ws, size_t ws_size,
                              hipStream_t stream) {
    const float* sr    = (const float*)d_in[0];
    const float* si    = (const float*)d_in[1];
    const float* theta = (const float*)d_in[2];
    const int* qubit_p = (const int*)d_in[3];
    const int* nq_p    = (const int*)d_in[4];

    const long long n = (long long)in_sizes[0];   // B * 2^nq elements per array
    float* out_r = (float*)d_out;
    float* out_i = out_r + n;

    const long long npairs   = n / 2;
    const long long nthreads = (npairs + 7) / 8;
    const int block = 256;
    const long long grid = (nthreads + block - 1) / block;

    rx_gate_kernel<<<dim3((unsigned)grid), dim3(block), 0, stream>>>(
        sr, si, theta, qubit_p, nq_p, out_r, out_i, npairs);
}

// Round 4
// 189.087 us; speedup vs baseline: 1.4841x; 1.4841x over previous
//
#include <hip/hip_runtime.h>

// RX(theta) on `qubit` of a [B, 2^nq] complex state (real/imag split, fp32).
//   nr0 = c*r0 + s*i1 ; ni0 = c*i0 - s*r1
//   nr1 = c*r1 + s*i0 ; ni1 = c*i1 - s*r0
// c = cos(theta/2), s = sin(theta/2), pair stride = right = 2^(nq-q-1).
//
// Pure stream: 4 pairs/thread, one 16B vector per stream per thread so every
// load/store instruction is perfectly coalesced across the wave (16B/lane at
// 16B lane stride). Nontemporal hints since data is touched exactly once.

typedef float f32x4 __attribute__((ext_vector_type(4)));

__global__ void __launch_bounds__(256)
rx_gate_kernel(const float* __restrict__ sr,
               const float* __restrict__ si,
               const float* __restrict__ theta,
               const int* __restrict__ qubit_p,
               const int* __restrict__ nq_p,
               float* __restrict__ out_r,
               float* __restrict__ out_i,
               long long npairs) {
    long long t = (long long)blockIdx.x * blockDim.x + threadIdx.x;
    long long p = t * 4;  // first pair index handled by this thread
    if (p >= npairs) return;

    const int shift = nq_p[0] - qubit_p[0] - 1;   // log2(right)
    const long long right = 1ll << shift;
    const long long mask = right - 1;

    const float half = 0.5f * theta[0];
    const float c = cosf(half);
    const float s = sinf(half);

    if (((right & 3) == 0) && (p + 4 <= npairs)) {
        // vector path: 4 consecutive pairs, contiguous, 16B-aligned
        const long long idx0 = ((p >> shift) << (shift + 1)) | (p & mask);

        const f32x4 R0 = __builtin_nontemporal_load((const f32x4*)(sr + idx0));
        const f32x4 R1 = __builtin_nontemporal_load((const f32x4*)(sr + idx0 + right));
        const f32x4 I0 = __builtin_nontemporal_load((const f32x4*)(si + idx0));
        const f32x4 I1 = __builtin_nontemporal_load((const f32x4*)(si + idx0 + right));

        f32x4 NR0, NR1, NI0, NI1;
#pragma unroll
        for (int k = 0; k < 4; ++k) {
            NR0[k] = fmaf(c, R0[k],  s * I1[k]);
            NI0[k] = fmaf(c, I0[k], -s * R1[k]);
            NR1[k] = fmaf(c, R1[k],  s * I0[k]);
            NI1[k] = fmaf(c, I1[k], -s * R0[k]);
        }

        __builtin_nontemporal_store(NR0, (f32x4*)(out_r + idx0));
        __builtin_nontemporal_store(NR1, (f32x4*)(out_r + idx0 + right));
        __builtin_nontemporal_store(NI0, (f32x4*)(out_i + idx0));
        __builtin_nontemporal_store(NI1, (f32x4*)(out_i + idx0 + right));
    } else {
        // scalar fallback (tail, or right < 4)
        for (int k = 0; k < 4; ++k) {
            const long long pk = p + k;
            if (pk >= npairs) break;
            const long long idx = ((pk >> shift) << (shift + 1)) | (pk & mask);
            const float r0 = sr[idx];
            const float r1 = sr[idx + right];
            const float i0 = si[idx];
            const float i1 = si[idx + right];
            out_r[idx]         = fmaf(c, r0,  s * i1);
            out_i[idx]         = fmaf(c, i0, -s * r1);
            out_r[idx + right] = fmaf(c, r1,  s * i0);
            out_i[idx + right] = fmaf(c, i1, -s * r0);
        }
    }
}

extern "C" void kernel_launch(void* const* d_in, const int* in_sizes, int n_in,
                              void* d_out, int out_size, void* d_ws, size_t ws_size,
                              hipStream_t stream) {
    const float* sr    = (const float*)d_in[0];
    const float* si    = (const float*)d_in[1];
    const float* theta = (const float*)d_in[2];
    const int* qubit_p = (const int*)d_in[3];
    const int* nq_p    = (const int*)d_in[4];

    const long long n = (long long)in_sizes[0];   // B * 2^nq elements per array
    float* out_r = (float*)d_out;
    float* out_i = out_r + n;

    const long long npairs   = n / 2;
    const long long nthreads = (npairs + 3) / 4;
    const int block = 256;
    const long long grid = (nthreads + block - 1) / block;

    rx_gate_kernel<<<dim3((unsigned)grid), dim3(block), 0, stream>>>(
        sr, si, theta, qubit_p, nq_p, out_r, out_i, npairs);
}